// Round 18
// baseline (34.724 us; speedup 1.0000x reference)
//
#include <hip/hip_runtime.h>

#define DIM 120
#define NB 16            // batch rows per block
#define NBP 20           // padded LDS stride in dwords (b128-aligned)
#define BLOCK 256        // one thread per output row
#define NG (NB / 4)      // float4 groups along b
#define NXCD 8
#define SMEM_FLOATS (2 * DIM * NBP)   // 19.2 KB staging, overlaid by 16 KB exchange
#define PAL_MAX 256

typedef float f32x4 __attribute__((ext_vector_type(4)));   // nt-store-legal vec4

// Single fused kernel: cooperative CSR decode + R16 hot loop + NT burst stores.
__global__ __launch_bounds__(BLOCK, 8) void tp_kernel(
    const float* __restrict__ in1, const float* __restrict__ in2,
    const float* __restrict__ pal, int paln,
    const int* __restrict__ i1, const int* __restrict__ i2,
    const int* __restrict__ oi, const int* __restrict__ cb,
    float* __restrict__ out, int H, int K, int nbx) {
    __shared__ __align__(16) float smem[SMEM_FLOATS];
    __shared__ int rs[BLOCK + 1];
    __shared__ float pal_lds[PAL_MAX];
    __shared__ int cnt[4];

    float* __restrict__ s1t = smem;
    float* __restrict__ s2t = smem + DIM * NBP;
    const int tid = threadIdx.x;

    // bijective XCD-chunked swizzle over the o-block dimension
    int x = blockIdx.x;
    {
        const int q = nbx / NXCD, r = nbx % NXCD;
        const int xcd = x % NXCD, pos = x / NXCD;
        x = (xcd < r) ? (xcd * (q + 1) + pos) : (r * (q + 1) + (xcd - r) * q + pos);
    }
    const int o0 = x * BLOCK;

    if (tid < 4) cnt[tid] = 0;
    for (int t = tid; t < paln && t < PAL_MAX; t += BLOCK) pal_lds[t] = pal[t];

    // --- stage NB batch-rows transposed to [d][b] (bulk loads issued early) ---
    const int b0 = blockIdx.y * NB;
    for (int t = tid; t < 2 * DIM * NG; t += BLOCK) {
        const int arr = (t >= DIM * NG);
        const int c = arr ? t - DIM * NG : t;
        const int d = c % DIM;
        const int g = c / DIM;
        const float* __restrict__ src = arr ? in2 : in1;
        const size_t base = (size_t)(b0 + 4 * g) * DIM + d;
        float4 v;
        v.x = src[base + 0 * DIM];
        v.y = src[base + 1 * DIM];
        v.z = src[base + 2 * DIM];
        v.w = src[base + 3 * DIM];
        float* dst = arr ? s2t : s1t;
        *(float4*)(dst + d * NBP + 4 * g) = v;
    }
    __syncthreads();   // B1: cnt zeroed + staging visible

    // --- cooperative 2-round lower_bound for o0 and v1 = min(o0+BLOCK, H) ---
    const int v1 = (o0 + BLOCK < H) ? (o0 + BLOCK) : H;
    const int stride = (K + BLOCK - 1) / BLOCK;
    {
        const size_t p = (size_t)tid * stride;
        const bool valid = p < (size_t)K;
        const int vi = oi[valid ? p : (size_t)(K - 1)];
        const unsigned long long m0 = __ballot(valid && (vi < o0));
        const unsigned long long m1 = __ballot(valid && (vi < v1));
        if ((tid & 63) == 0) {
            atomicAdd(&cnt[0], (int)__popcll(m0));
            atomicAdd(&cnt[1], (int)__popcll(m1));
        }
    }
    __syncthreads();   // B2
    const int c0 = cnt[0], c1 = cnt[1];
    const int lo0 = (c0 == 0) ? 0 : (c0 - 1) * stride + 1;
    const int lo1 = (c1 == 0) ? 0 : (c1 - 1) * stride + 1;
    {
        const int kk0 = lo0 + tid;
        const int kk1 = lo1 + tid;
        const bool p0 = (tid < stride) && (kk0 < K) && (oi[kk0] < o0);
        const bool p1 = (tid < stride) && (kk1 < K) && (oi[kk1] < v1);
        const unsigned long long m0 = __ballot(p0);
        const unsigned long long m1 = __ballot(p1);
        if ((tid & 63) == 0) {
            atomicAdd(&cnt[2], (int)__popcll(m0));
            atomicAdd(&cnt[3], (int)__popcll(m1));
        }
    }
    __syncthreads();   // B3
    const int k0b = lo0 + cnt[2];
    const int k1b = lo1 + cnt[3];

    // --- build rs[0..BLOCK] by diff-scan over [k0b, k1b) ---
    for (int kk = k0b + tid; kk < k1b; kk += BLOCK) {
        const int cur = oi[kk];
        const int prevv = (kk == 0) ? -1 : oi[kk - 1];
        for (int o = (prevv + 1 > o0 ? prevv + 1 : o0); o <= cur; ++o)
            rs[o - o0] = kk;
    }
    if (tid == 0) {
        const int prevv = (k1b == 0) ? -1 : oi[k1b - 1];
        const int lo = (prevv + 1 > o0) ? prevv + 1 : o0;
        for (int o = lo; o <= o0 + BLOCK; ++o)
            rs[o - o0] = k1b;
    }
    __syncthreads();   // B4

    const int o = o0 + tid;
    const bool act = (o < H);

    float acc[NB];
#pragma unroll
    for (int b = 0; b < NB; ++b) acc[b] = 0.0f;

    if (act) {
        const int k0 = rs[tid];
        const int k1 = rs[tid + 1];
        for (int k = k0; k < k1; ++k) {
            const int a = i1[k];
            const int c = i2[k];
            const float v = pal_lds[cb[k]];
            const float4* __restrict__ pa = (const float4*)(s1t + a * NBP);
            const float4* __restrict__ pc = (const float4*)(s2t + c * NBP);
#pragma unroll
            for (int j = 0; j < NG; ++j) {
                const float4 x4 = pa[j];
                const float4 y4 = pc[j];
                acc[4 * j + 0] = fmaf(v * x4.x, y4.x, acc[4 * j + 0]);
                acc[4 * j + 1] = fmaf(v * x4.y, y4.y, acc[4 * j + 1]);
                acc[4 * j + 2] = fmaf(v * x4.z, y4.z, acc[4 * j + 2]);
                acc[4 * j + 3] = fmaf(v * x4.w, y4.w, acc[4 * j + 3]);
            }
        }
    }
    __syncthreads();   // staging reads complete before overwriting smem

    if (o0 + BLOCK <= H) {
        // exchange: outbuf[b][t] overlaid on smem, stride-1 conflict-free
#pragma unroll
        for (int b = 0; b < NB; ++b)
            smem[b * BLOCK + tid] = acc[b];
        __syncthreads();
        const int wave = tid >> 6;
        const int lane = tid & 63;
        f32x4 vv[NB / 4];
#pragma unroll
        for (int it = 0; it < NB / 4; ++it)
            vv[it] = *(const f32x4*)(smem + (it * 4 + wave) * BLOCK + 4 * lane);
#pragma unroll
        for (int it = 0; it < NB / 4; ++it)
            __builtin_nontemporal_store(
                vv[it],
                (f32x4*)(out + (size_t)(b0 + it * 4 + wave) * H + o0 + 4 * lane));
    } else if (act) {
#pragma unroll
        for (int b = 0; b < NB; ++b)
            __builtin_nontemporal_store(acc[b], &out[(size_t)(b0 + b) * H + o]);
    }
}

extern "C" void kernel_launch(void* const* d_in, const int* in_sizes, int n_in,
                              void* d_out, int out_size, void* d_ws, size_t ws_size,
                              hipStream_t stream) {
    const float* in1 = (const float*)d_in[0];
    const float* in2 = (const float*)d_in[1];
    const float* pal = (const float*)d_in[2];
    const int*   i1  = (const int*)d_in[3];
    const int*   i2  = (const int*)d_in[4];
    const int*   oi  = (const int*)d_in[5];
    const int*   cb  = (const int*)d_in[6];

    const int paln = in_sizes[2];
    const int K = in_sizes[3];
    const int B = in_sizes[0] / DIM;   // 2048
    const int H = out_size / B;        // 14400

    const int nbx = (H + BLOCK - 1) / BLOCK;   // 57
    dim3 grid(nbx, B / NB);
    tp_kernel<<<grid, BLOCK, 0, stream>>>(in1, in2, pal, paln, i1, i2, oi, cb,
                                          (float*)d_out, H, K, nbx);
}